// Round 4
// baseline (425.754 us; speedup 1.0000x reference)
//
#include <hip/hip_runtime.h>

#define BB 128
#define TT 256
#define CCH 384
#define NHH 6
#define HSZ 64
#define BTT (BB*TT)
#define QKVLD 1152

typedef unsigned short u16;
typedef unsigned int   u32;
typedef __attribute__((ext_vector_type(8))) short  short8;   // 8 x bf16 (4 VGPR)
typedef __attribute__((ext_vector_type(4))) float  floatx4;  // MFMA C/D

__device__ __forceinline__ u16 f2bf(float f) {
  union { float f; u32 i; } v; v.f = f; u32 x = v.i;
  return (u16)((x + 0x7fffu + ((x >> 16) & 1u)) >> 16);
}
__device__ __forceinline__ float bf2f(u16 w) {
  union { u32 i; float f; } v; v.i = ((u32)w) << 16; return v.f;
}

// async global->LDS, 16B per lane; LDS dest is wave-uniform base + lane*16
__device__ __forceinline__ void gll16(const u16* g, u16* l) {
  __builtin_amdgcn_global_load_lds((const __attribute__((address_space(1))) void*)g,
                                   (__attribute__((address_space(3))) void*)l, 16, 0, 0);
}

// ---------------- LayerNorm: fp32/bf16 in -> bf16 out, one wave per row, 4 rows/block ----
template <int INBF>
__global__ __launch_bounds__(256) void ln_kernel(const void* __restrict__ xv,
                                                 const float* __restrict__ g,
                                                 const float* __restrict__ b,
                                                 u16* __restrict__ out) {
  int row = blockIdx.x * 4 + (threadIdx.x >> 6);
  int lane = threadIdx.x & 63;
  float vals[6];
  float sum = 0.f;
  if (INBF) {
    const u16* xr = (const u16*)xv + (size_t)row * CCH;
#pragma unroll
    for (int i = 0; i < 6; ++i) { vals[i] = bf2f(xr[lane + (i << 6)]); sum += vals[i]; }
  } else {
    const float* xr = (const float*)xv + (size_t)row * CCH;
#pragma unroll
    for (int i = 0; i < 6; ++i) { vals[i] = xr[lane + (i << 6)]; sum += vals[i]; }
  }
#pragma unroll
  for (int off = 32; off; off >>= 1) sum += __shfl_xor(sum, off);
  float mean = sum * (1.f / 384.f);
  float vs = 0.f;
#pragma unroll
  for (int i = 0; i < 6; ++i) { float d = vals[i] - mean; vs += d * d; }
#pragma unroll
  for (int off = 32; off; off >>= 1) vs += __shfl_xor(vs, off);
  float rinv = rsqrtf(vs * (1.f / 384.f) + 1e-5f);
  u16* orow = out + (size_t)row * CCH;
#pragma unroll
  for (int i = 0; i < 6; ++i) {
    int c = lane + (i << 6);
    orow[c] = f2bf((vals[i] - mean) * rinv * g[c] + b[c]);
  }
}

// ---------------- merged weight repack: all four weights, one launch ----------------
// wqkv_t: rows n=h*64+d of (1152,384); wp_t (384,384); w1_t (1536,384); w2_t (384,1536)
__global__ void repack_all(const float* __restrict__ wq, const float* __restrict__ wk,
                           const float* __restrict__ wv, const float* __restrict__ wproj,
                           const float* __restrict__ w1, const float* __restrict__ w2,
                           u16* __restrict__ wqkv_t, u16* __restrict__ wp_t,
                           u16* __restrict__ w1_t, u16* __restrict__ w2_t) {
  int idx = blockIdx.x * 256 + threadIdx.x;
  if (idx < 147456) {
    int n = idx / CCH, kk = idx % CCH;
    size_t src = ((size_t)(n >> 6) * CCH + kk) * 64 + (n & 63);
    wqkv_t[idx]          = f2bf(wq[src]);
    wqkv_t[idx + 147456] = f2bf(wk[src]);
    wqkv_t[idx + 294912] = f2bf(wv[src]);
  } else if (idx < 294912) {
    int i = idx - 147456;
    int n = i / CCH, kk = i % CCH;
    wp_t[i] = f2bf(wproj[(size_t)kk * CCH + n]);
  } else if (idx < 294912 + 589824) {
    int i = idx - 294912;
    int n = i / CCH, kk = i % CCH;
    w1_t[i] = f2bf(w1[(size_t)kk * 1536 + n]);
  } else if (idx < 294912 + 2 * 589824) {
    int i = idx - 294912 - 589824;
    int n = i / 1536, kk = i % 1536;
    w2_t[i] = f2bf(w2[(size_t)kk * CCH + n]);
  }
}

// ---- MFMA GEMM: C[M,N] = A[M,K] * W[N,K]^T, 128x128 tile, BK=32, double-buffered ----
// 128 threads = 2 waves; wave tile 64x128 (4x8 MFMA accs) for 42.7 FLOP/LDS-byte.
// Wave 0 stages the A tile, wave 1 the B tile (8 x global_load_lds width-16 each).
template <int BIAS, int RES, int RELU, int OUTBF, int RESBF>
__global__ __launch_bounds__(128) void gemm_mfma(const u16* __restrict__ A,
                                                 const u16* __restrict__ W,
                                                 const float* __restrict__ bias,
                                                 const void* __restrict__ resv,
                                                 void* __restrict__ outv,
                                                 int M, int N, int K) {
  __shared__ __align__(16) u16 As[2][128 * 32];
  __shared__ __align__(16) u16 Bs[2][128 * 32];
  const int tid = threadIdx.x;
  const int lane = tid & 63;
  const int w = tid >> 6;                 // 0: A-loader + rows 0-63; 1: B-loader + rows 64-127
  const int m0 = blockIdx.y * 128, n0 = blockIdx.x * 128;
  const int lm = lane & 15, qd = lane >> 4;

  floatx4 acc[4][8];
  floatx4 zero4 = {0.f, 0.f, 0.f, 0.f};
#pragma unroll
  for (int i = 0; i < 4; ++i)
#pragma unroll
    for (int j = 0; j < 8; ++j) acc[i][j] = zero4;

  // loader: this wave stages one 128x32 tile (8 calls of 16 rows each)
  // call c, lane l: row = 16c + (l>>2), chunk = (l&3) ^ ((row>>1)&3)  (XOR swizzle)
  const u16* src[8];
  {
    const u16* P = (w == 0) ? (A + (size_t)m0 * K) : (W + (size_t)n0 * K);
#pragma unroll
    for (int c = 0; c < 8; ++c) {
      int row = 16 * c + (lane >> 2);
      int ch = (lane & 3) ^ ((row >> 1) & 3);
      src[c] = P + (size_t)row * K + ch * 8;
    }
  }
  u16* dstbase0 = (w == 0) ? As[0] : Bs[0];
  u16* dstbase1 = (w == 0) ? As[1] : Bs[1];

  // prologue: stage k0=0 into buffer 0
#pragma unroll
  for (int c = 0; c < 8; ++c) gll16(src[c], dstbase0 + c * 512);

  int ib = 0;
  for (int k0 = 0; k0 < K; k0 += 32, ib ^= 1) {
    __syncthreads();  // drains prefetch issued a full compute-phase ago
    int kn = k0 + 32;
    if (kn < K) {
      u16* db = ib ? dstbase0 : dstbase1;
#pragma unroll
      for (int c = 0; c < 8; ++c) gll16(src[c] + kn, db + c * 512);
    }
    short8 af[4], bf[8];
#pragma unroll
    for (int i = 0; i < 4; ++i) {
      int rm = 64 * w + 16 * i + lm;
      af[i] = *(const short8*)&As[ib][rm * 32 + (qd ^ ((rm >> 1) & 3)) * 8];
    }
#pragma unroll
    for (int j = 0; j < 8; ++j) {
      int rn = 16 * j + lm;
      bf[j] = *(const short8*)&Bs[ib][rn * 32 + (qd ^ ((rn >> 1) & 3)) * 8];
    }
#pragma unroll
    for (int i = 0; i < 4; ++i)
#pragma unroll
      for (int j = 0; j < 8; ++j)
        acc[i][j] = __builtin_amdgcn_mfma_f32_16x16x32_bf16(af[i], bf[j], acc[i][j], 0, 0, 0);
  }

  // epilogue: C/D layout col=lm, row=qd*4+r
#pragma unroll
  for (int i = 0; i < 4; ++i) {
    int row0 = m0 + 64 * w + 16 * i + qd * 4;
#pragma unroll
    for (int j = 0; j < 8; ++j) {
      int col = n0 + 16 * j + lm;
      float bb = 0.f;
      if (BIAS) bb = bias[col];
#pragma unroll
      for (int r = 0; r < 4; ++r) {
        size_t idx = (size_t)(row0 + r) * N + col;
        float val = acc[i][j][r] + bb;
        if (RES) val += RESBF ? bf2f(((const u16*)resv)[idx]) : ((const float*)resv)[idx];
        if (RELU) val = fmaxf(val, 0.f);
        if (OUTBF) ((u16*)outv)[idx] = f2bf(val);
        else       ((float*)outv)[idx] = val;
      }
    }
  }
}

// ---------------- MFMA attention, column(query-axis) softmax ----------------
// qkv: (B*T, 1152) bf16, q at col h*64, k at 384+h*64, v at 768+h*64
// out: (B*T, 384) bf16.  scale = 384^-0.5.
#define ASCALE 0.051031036307982884f

__global__ __launch_bounds__(1024) void attn_mfma(const u16* __restrict__ qkv,
                                                  u16* __restrict__ out) {
  __shared__ __align__(16) char lds_raw[36864 + 20480 + 2048];
  u16*   Ks       = (u16*)lds_raw;
  u16*   VT       = (u16*)lds_raw;
  float* partials = (float*)(lds_raw + 36864);
  u16*   stage    = (u16*)(lds_raw + 36864);
  float* gmax     = (float*)(lds_raw + 57344);
  float* linv     = (float*)(lds_raw + 58368);

  const int tid = threadIdx.x;
  const int lane = tid & 63;
  const int w = tid >> 6;           // wave 0..15 owns S rows [16w,16w+16)
  const int lm = lane & 15, qd = lane >> 4;
  const int b = blockIdx.x / NHH, h = blockIdx.x % NHH;
  const size_t rowbase = (size_t)b * TT;
  const u16* qp = qkv + rowbase * QKVLD + h * HSZ;
  const u16* kp = qp + 384;
  const u16* vp = qp + 768;

  {
    int s = tid >> 2, c4 = tid & 3;
    const u16* src = kp + (size_t)s * QKVLD;
    *(uint4*)&Ks[s * 72 + c4 * 8]       = *(const uint4*)(src + c4 * 8);
    *(uint4*)&Ks[s * 72 + (c4 + 4) * 8] = *(const uint4*)(src + (c4 + 4) * 8);
  }
  short8 qf0, qf1;
  {
    const u16* qrow = qp + (size_t)(16 * w + lm) * QKVLD + qd * 8;
    qf0 = *(const short8*)(qrow);
    qf1 = *(const short8*)(qrow + 32);
  }
  __syncthreads();

  floatx4 acc[16];
  floatx4 zero4 = {0.f, 0.f, 0.f, 0.f};
#pragma unroll
  for (int tc = 0; tc < 16; ++tc) acc[tc] = zero4;

#pragma unroll
  for (int tc = 0; tc < 16; ++tc) {
    if (tc <= w) {
      int sr = 16 * tc + lm;
      short8 kf0 = *(const short8*)&Ks[sr * 72 + qd * 8];
      short8 kf1 = *(const short8*)&Ks[sr * 72 + 32 + qd * 8];
      acc[tc] = __builtin_amdgcn_mfma_f32_16x16x32_bf16(qf0, kf0, acc[tc], 0, 0, 0);
      acc[tc] = __builtin_amdgcn_mfma_f32_16x16x32_bf16(qf1, kf1, acc[tc], 0, 0, 0);
    }
  }

  const int rb = 16 * w + qd * 4;
  float pmax[16];
#pragma unroll
  for (int tc = 0; tc < 16; ++tc) {
    float m = -1e30f;
    if (tc <= w) {
      int sc = 16 * tc + lm;
#pragma unroll
      for (int r = 0; r < 4; ++r) {
        float vv = acc[tc][r] * ASCALE;
        vv = (rb + r >= sc) ? vv : -1e30f;
        acc[tc][r] = vv;
        m = fmaxf(m, vv);
      }
    }
    m = fmaxf(m, __shfl_xor(m, 16));
    m = fmaxf(m, __shfl_xor(m, 32));
    pmax[tc] = m;
  }
  if (lane < 16) {
#pragma unroll
    for (int tc = 0; tc < 16; ++tc) partials[w * 256 + tc * 16 + lane] = pmax[tc];
  }
  __syncthreads();
  if (tid < 256) {
    float m = partials[tid];
#pragma unroll
    for (int i = 1; i < 16; ++i) m = fmaxf(m, partials[i * 256 + tid]);
    gmax[tid] = m;
  }
  __syncthreads();

  float psum[16];
#pragma unroll
  for (int tc = 0; tc < 16; ++tc) {
    float s = 0.f;
    if (tc <= w) {
      float gm = gmax[tc * 16 + lm];
#pragma unroll
      for (int r = 0; r < 4; ++r) {
        float e = (acc[tc][r] > -1e29f) ? __expf(acc[tc][r] - gm) : 0.f;
        acc[tc][r] = e;
        s += e;
      }
    }
    s += __shfl_xor(s, 16);
    s += __shfl_xor(s, 32);
    psum[tc] = s;
  }
  if (lane < 16) {
#pragma unroll
    for (int tc = 0; tc < 16; ++tc) partials[w * 256 + tc * 16 + lane] = psum[tc];
  }
  __syncthreads();
  if (tid < 256) {
    float s = partials[tid];
#pragma unroll
    for (int i = 1; i < 16; ++i) s += partials[i * 256 + tid];
    linv[tid] = 1.f / s;
  }
  __syncthreads();

  {
    int s = tid >> 2, dg = (tid & 3) * 16;
    const u16* vrow = vp + (size_t)s * QKVLD + dg;
    u16 tmp[16];
    *(uint4*)&tmp[0] = *(const uint4*)(vrow);
    *(uint4*)&tmp[8] = *(const uint4*)(vrow + 8);
#pragma unroll
    for (int j = 0; j < 16; ++j) VT[(dg + j) * 264 + s] = tmp[j];
  }
  __syncthreads();

  u16* mst = stage + w * 640;
  floatx4 oacc[4];
#pragma unroll
  for (int nt = 0; nt < 4; ++nt) oacc[nt] = zero4;

#pragma unroll
  for (int c = 0; c < 8; ++c) {
    if (2 * c <= w) {
#pragma unroll
      for (int tt = 0; tt < 2; ++tt) {
        int tc = 2 * c + tt;
        float li = (tc <= w) ? linv[tc * 16 + lm] : 0.f;
#pragma unroll
        for (int r = 0; r < 4; ++r) {
          float pv = (tc <= w) ? acc[tc][r] * li : 0.f;
          mst[(qd * 4 + r) * 40 + tt * 16 + lm] = f2bf(pv);
        }
      }
      asm volatile("s_waitcnt lgkmcnt(0)" ::: "memory");
      short8 pf = *(const short8*)&mst[lm * 40 + qd * 8];
#pragma unroll
      for (int nt = 0; nt < 4; ++nt) {
        short8 vf = *(const short8*)&VT[(nt * 16 + lm) * 264 + c * 32 + qd * 8];
        oacc[nt] = __builtin_amdgcn_mfma_f32_16x16x32_bf16(pf, vf, oacc[nt], 0, 0, 0);
      }
      asm volatile("" ::: "memory");
    }
  }

  u16* ob = out + rowbase * CCH + h * HSZ;
#pragma unroll
  for (int nt = 0; nt < 4; ++nt) {
#pragma unroll
    for (int r = 0; r < 4; ++r) {
      int t = 16 * w + qd * 4 + r;
      ob[(size_t)t * CCH + nt * 16 + lm] = f2bf(oacc[nt][r]);
    }
  }
}

// ---------------- launch ----------------
extern "C" void kernel_launch(void* const* d_in, const int* in_sizes, int n_in,
                              void* d_out, int out_size, void* d_ws, size_t ws_size,
                              hipStream_t stream) {
  const float* x     = (const float*)d_in[0];
  const float* wq    = (const float*)d_in[1];
  const float* wk    = (const float*)d_in[2];
  const float* wv    = (const float*)d_in[3];
  const float* wproj = (const float*)d_in[4];
  const float* bproj = (const float*)d_in[5];
  const float* w1    = (const float*)d_in[6];
  const float* b1    = (const float*)d_in[7];
  const float* w2    = (const float*)d_in[8];
  const float* b2    = (const float*)d_in[9];
  const float* ln1g  = (const float*)d_in[10];
  const float* ln1b  = (const float*)d_in[11];
  const float* ln2g  = (const float*)d_in[12];
  const float* ln2b  = (const float*)d_in[13];
  float* out = (float*)d_out;
  (void)in_sizes; (void)n_in; (void)out_size; (void)ws_size;

  char* ws = (char*)d_ws;
  size_t off = 0;
  auto alloc = [&](size_t bytes) -> void* {
    void* p = ws + off;
    off += (bytes + 255) & ~(size_t)255;
    return p;
  };

  u16* wqkv_t = (u16*)alloc((size_t)QKVLD * CCH * 2);         // (1152,384)
  u16* wp_t   = (u16*)alloc((size_t)CCH * CCH * 2);           // (384,384)
  u16* w1_t   = (u16*)alloc((size_t)4 * CCH * CCH * 2);       // (1536,384)
  u16* w2_t   = (u16*)alloc((size_t)CCH * 4 * CCH * 2);       // (384,1536)
  u16*   h_b  = (u16*)alloc((size_t)BTT * CCH * 2);           // LN1 / attn-out / LN2
  u16*   x2   = (u16*)alloc((size_t)BTT * CCH * 2);           // bf16 residual stream
  u16*   qkv_b = (u16*)alloc((size_t)BTT * 4 * CCH * 2);      // (BT,1152) then u (BT,1536)
  u16*   u_b   = qkv_b;

  repack_all<<<5760, 256, 0, stream>>>(wq, wk, wv, wproj, w1, w2,
                                       wqkv_t, wp_t, w1_t, w2_t);

  // LN1 -> h
  ln_kernel<0><<<BTT / 4, 256, 0, stream>>>(x, ln1g, ln1b, h_b);

  // fused QKV: (BT,1152)
  gemm_mfma<0, 0, 0, 1, 0><<<dim3(9, 256), 128, 0, stream>>>(h_b, wqkv_t, nullptr, nullptr,
                                                             qkv_b, BTT, QKVLD, CCH);
  // attention -> h_b (h dead)
  attn_mfma<<<BB * NHH, 1024, 0, stream>>>(qkv_b, h_b);

  // x2 = x + attn @ wproj + bproj  (bf16 out)
  gemm_mfma<1, 1, 0, 1, 0><<<dim3(3, 256), 128, 0, stream>>>(h_b, wp_t, bproj, x, x2,
                                                             BTT, CCH, CCH);
  // LN2 -> h_b (attn dead)
  ln_kernel<1><<<BTT / 4, 256, 0, stream>>>(x2, ln2g, ln2b, h_b);

  // u = relu(h2 @ w1 + b1): (BT,1536)
  gemm_mfma<1, 0, 1, 1, 0><<<dim3(12, 256), 128, 0, stream>>>(h_b, w1_t, b1, nullptr, u_b,
                                                              BTT, 4 * CCH, CCH);
  // out = x2 + u @ w2 + b2  (fp32 out, bf16 res)
  gemm_mfma<1, 1, 0, 0, 1><<<dim3(3, 256), 128, 0, stream>>>(u_b, w2_t, b2, x2, out,
                                                             BTT, CCH, 4 * CCH);
}

// Round 5
// 399.283 us; speedup vs baseline: 1.0663x; 1.0663x over previous
//
#include <hip/hip_runtime.h>

#define BB 128
#define TT 256
#define CCH 384
#define NHH 6
#define HSZ 64
#define BTT (BB*TT)
#define QKVLD 1152

typedef unsigned short u16;
typedef unsigned int   u32;
typedef __attribute__((ext_vector_type(8))) short  short8;   // 8 x bf16 (4 VGPR)
typedef __attribute__((ext_vector_type(4))) float  floatx4;  // MFMA C/D

__device__ __forceinline__ u16 f2bf(float f) {
  union { float f; u32 i; } v; v.f = f; u32 x = v.i;
  return (u16)((x + 0x7fffu + ((x >> 16) & 1u)) >> 16);
}
__device__ __forceinline__ float bf2f(u16 w) {
  union { u32 i; float f; } v; v.i = ((u32)w) << 16; return v.f;
}

// async global->LDS, 16B per lane; LDS dest is wave-uniform base + lane*16
__device__ __forceinline__ void gll16(const u16* g, u16* l) {
  __builtin_amdgcn_global_load_lds((const __attribute__((address_space(1))) void*)g,
                                   (__attribute__((address_space(3))) void*)l, 16, 0, 0);
}

// ---------------- LayerNorm: fp32/bf16 in -> bf16 out, one wave per row, 4 rows/block ----
template <int INBF>
__global__ __launch_bounds__(256) void ln_kernel(const void* __restrict__ xv,
                                                 const float* __restrict__ g,
                                                 const float* __restrict__ b,
                                                 u16* __restrict__ out) {
  int row = blockIdx.x * 4 + (threadIdx.x >> 6);
  int lane = threadIdx.x & 63;
  float vals[6];
  float sum = 0.f;
  if (INBF) {
    const u16* xr = (const u16*)xv + (size_t)row * CCH;
#pragma unroll
    for (int i = 0; i < 6; ++i) { vals[i] = bf2f(xr[lane + (i << 6)]); sum += vals[i]; }
  } else {
    const float* xr = (const float*)xv + (size_t)row * CCH;
#pragma unroll
    for (int i = 0; i < 6; ++i) { vals[i] = xr[lane + (i << 6)]; sum += vals[i]; }
  }
#pragma unroll
  for (int off = 32; off; off >>= 1) sum += __shfl_xor(sum, off);
  float mean = sum * (1.f / 384.f);
  float vs = 0.f;
#pragma unroll
  for (int i = 0; i < 6; ++i) { float d = vals[i] - mean; vs += d * d; }
#pragma unroll
  for (int off = 32; off; off >>= 1) vs += __shfl_xor(vs, off);
  float rinv = rsqrtf(vs * (1.f / 384.f) + 1e-5f);
  u16* orow = out + (size_t)row * CCH;
#pragma unroll
  for (int i = 0; i < 6; ++i) {
    int c = lane + (i << 6);
    orow[c] = f2bf((vals[i] - mean) * rinv * g[c] + b[c]);
  }
}

// ---------------- merged weight repack: all four weights, one launch ----------------
__global__ void repack_all(const float* __restrict__ wq, const float* __restrict__ wk,
                           const float* __restrict__ wv, const float* __restrict__ wproj,
                           const float* __restrict__ w1, const float* __restrict__ w2,
                           u16* __restrict__ wqkv_t, u16* __restrict__ wp_t,
                           u16* __restrict__ w1_t, u16* __restrict__ w2_t) {
  int idx = blockIdx.x * 256 + threadIdx.x;
  if (idx < 147456) {
    int n = idx / CCH, kk = idx % CCH;
    size_t src = ((size_t)(n >> 6) * CCH + kk) * 64 + (n & 63);
    wqkv_t[idx]          = f2bf(wq[src]);
    wqkv_t[idx + 147456] = f2bf(wk[src]);
    wqkv_t[idx + 294912] = f2bf(wv[src]);
  } else if (idx < 294912) {
    int i = idx - 147456;
    int n = i / CCH, kk = i % CCH;
    wp_t[i] = f2bf(wproj[(size_t)kk * CCH + n]);
  } else if (idx < 294912 + 589824) {
    int i = idx - 294912;
    int n = i / CCH, kk = i % CCH;
    w1_t[i] = f2bf(w1[(size_t)kk * 1536 + n]);
  } else if (idx < 294912 + 2 * 589824) {
    int i = idx - 294912 - 589824;
    int n = i / 1536, kk = i % 1536;
    w2_t[i] = f2bf(w2[(size_t)kk * CCH + n]);
  }
}

// ---- MFMA GEMM: C[M,N] = A[M,K] * W[N,K]^T, 256x128 block tile, BK=32, dbuf ----
// 256 threads = 4 waves; wave tile 64x128 (4x8 MFMA accs), 42.7 FLOP/LDS-byte,
// 8 waves/CU (VGPR<=256 via launch_bounds, LDS 48KB). Wave w stages A rows
// [64w,64w+64) (4 gll16) + B rows [32w,32w+32) (2 gll16).
template <int BIAS, int RES, int RELU, int OUTBF, int RESBF>
__global__ __launch_bounds__(256, 2) void gemm_mfma(const u16* __restrict__ A,
                                                    const u16* __restrict__ W,
                                                    const float* __restrict__ bias,
                                                    const void* __restrict__ resv,
                                                    void* __restrict__ outv,
                                                    int M, int N, int K) {
  __shared__ __align__(16) u16 As[2][256 * 32];
  __shared__ __align__(16) u16 Bs[2][128 * 32];
  const int tid = threadIdx.x;
  const int lane = tid & 63;
  const int w = tid >> 6;                 // wave 0..3; owns C rows [64w,64w+64)
  const int m0 = blockIdx.y * 256, n0 = blockIdx.x * 128;
  const int lm = lane & 15, qd = lane >> 4;

  floatx4 acc[4][8];
  floatx4 zero4 = {0.f, 0.f, 0.f, 0.f};
#pragma unroll
  for (int i = 0; i < 4; ++i)
#pragma unroll
    for (int j = 0; j < 8; ++j) acc[i][j] = zero4;

  // loader sources: call c covers 16 rows; chunk = (l&3) ^ ((row>>1)&3) (XOR swizzle)
  const u16* srcA[4];
  const u16* srcB[2];
#pragma unroll
  for (int c = 0; c < 4; ++c) {
    int row = 64 * w + 16 * c + (lane >> 2);
    int ch = (lane & 3) ^ ((row >> 1) & 3);
    srcA[c] = A + (size_t)(m0 + row) * K + ch * 8;
  }
#pragma unroll
  for (int c = 0; c < 2; ++c) {
    int row = 32 * w + 16 * c + (lane >> 2);
    int ch = (lane & 3) ^ ((row >> 1) & 3);
    srcB[c] = W + (size_t)(n0 + row) * K + ch * 8;
  }
  const int dA = (64 * w) * 32;   // u16 offset of this wave's A region
  const int dB = (32 * w) * 32;

  // prologue: stage k0=0 into buffer 0
#pragma unroll
  for (int c = 0; c < 4; ++c) gll16(srcA[c], &As[0][dA + 512 * c]);
#pragma unroll
  for (int c = 0; c < 2; ++c) gll16(srcB[c], &Bs[0][dB + 512 * c]);

  int ib = 0;
  for (int k0 = 0; k0 < K; k0 += 32, ib ^= 1) {
    __syncthreads();  // drains prefetch issued a full compute-phase ago
    int kn = k0 + 32;
    if (kn < K) {
      int nb = ib ^ 1;
#pragma unroll
      for (int c = 0; c < 4; ++c) gll16(srcA[c] + kn, &As[nb][dA + 512 * c]);
#pragma unroll
      for (int c = 0; c < 2; ++c) gll16(srcB[c] + kn, &Bs[nb][dB + 512 * c]);
    }
    short8 af[4], bf[8];
#pragma unroll
    for (int i = 0; i < 4; ++i) {
      int rm = 64 * w + 16 * i + lm;
      af[i] = *(const short8*)&As[ib][rm * 32 + (qd ^ ((rm >> 1) & 3)) * 8];
    }
#pragma unroll
    for (int j = 0; j < 8; ++j) {
      int rn = 16 * j + lm;
      bf[j] = *(const short8*)&Bs[ib][rn * 32 + (qd ^ ((rn >> 1) & 3)) * 8];
    }
#pragma unroll
    for (int i = 0; i < 4; ++i)
#pragma unroll
      for (int j = 0; j < 8; ++j)
        acc[i][j] = __builtin_amdgcn_mfma_f32_16x16x32_bf16(af[i], bf[j], acc[i][j], 0, 0, 0);
  }

  // epilogue: C/D layout col=lm, row=qd*4+r
#pragma unroll
  for (int i = 0; i < 4; ++i) {
    int row0 = m0 + 64 * w + 16 * i + qd * 4;
#pragma unroll
    for (int j = 0; j < 8; ++j) {
      int col = n0 + 16 * j + lm;
      float bb = 0.f;
      if (BIAS) bb = bias[col];
#pragma unroll
      for (int r = 0; r < 4; ++r) {
        size_t idx = (size_t)(row0 + r) * N + col;
        float val = acc[i][j][r] + bb;
        if (RES) val += RESBF ? bf2f(((const u16*)resv)[idx]) : ((const float*)resv)[idx];
        if (RELU) val = fmaxf(val, 0.f);
        if (OUTBF) ((u16*)outv)[idx] = f2bf(val);
        else       ((float*)outv)[idx] = val;
      }
    }
  }
}

// ---------------- MFMA attention, column(query-axis) softmax ----------------
// qkv: (B*T, 1152) bf16, q at col h*64, k at 384+h*64, v at 768+h*64
// out: (B*T, 384) bf16.  scale = 384^-0.5.
#define ASCALE 0.051031036307982884f

__global__ __launch_bounds__(1024) void attn_mfma(const u16* __restrict__ qkv,
                                                  u16* __restrict__ out) {
  __shared__ __align__(16) char lds_raw[36864 + 20480 + 2048];
  u16*   Ks       = (u16*)lds_raw;
  u16*   VT       = (u16*)lds_raw;
  float* partials = (float*)(lds_raw + 36864);
  u16*   stage    = (u16*)(lds_raw + 36864);
  float* gmax     = (float*)(lds_raw + 57344);
  float* linv     = (float*)(lds_raw + 58368);

  const int tid = threadIdx.x;
  const int lane = tid & 63;
  const int w = tid >> 6;           // wave 0..15 owns S rows [16w,16w+16)
  const int lm = lane & 15, qd = lane >> 4;
  const int b = blockIdx.x / NHH, h = blockIdx.x % NHH;
  const size_t rowbase = (size_t)b * TT;
  const u16* qp = qkv + rowbase * QKVLD + h * HSZ;
  const u16* kp = qp + 384;
  const u16* vp = qp + 768;

  {
    int s = tid >> 2, c4 = tid & 3;
    const u16* src = kp + (size_t)s * QKVLD;
    *(uint4*)&Ks[s * 72 + c4 * 8]       = *(const uint4*)(src + c4 * 8);
    *(uint4*)&Ks[s * 72 + (c4 + 4) * 8] = *(const uint4*)(src + (c4 + 4) * 8);
  }
  short8 qf0, qf1;
  {
    const u16* qrow = qp + (size_t)(16 * w + lm) * QKVLD + qd * 8;
    qf0 = *(const short8*)(qrow);
    qf1 = *(const short8*)(qrow + 32);
  }
  __syncthreads();

  floatx4 acc[16];
  floatx4 zero4 = {0.f, 0.f, 0.f, 0.f};
#pragma unroll
  for (int tc = 0; tc < 16; ++tc) acc[tc] = zero4;

#pragma unroll
  for (int tc = 0; tc < 16; ++tc) {
    if (tc <= w) {
      int sr = 16 * tc + lm;
      short8 kf0 = *(const short8*)&Ks[sr * 72 + qd * 8];
      short8 kf1 = *(const short8*)&Ks[sr * 72 + 32 + qd * 8];
      acc[tc] = __builtin_amdgcn_mfma_f32_16x16x32_bf16(qf0, kf0, acc[tc], 0, 0, 0);
      acc[tc] = __builtin_amdgcn_mfma_f32_16x16x32_bf16(qf1, kf1, acc[tc], 0, 0, 0);
    }
  }

  const int rb = 16 * w + qd * 4;
  float pmax[16];
#pragma unroll
  for (int tc = 0; tc < 16; ++tc) {
    float m = -1e30f;
    if (tc <= w) {
      int sc = 16 * tc + lm;
#pragma unroll
      for (int r = 0; r < 4; ++r) {
        float vv = acc[tc][r] * ASCALE;
        vv = (rb + r >= sc) ? vv : -1e30f;
        acc[tc][r] = vv;
        m = fmaxf(m, vv);
      }
    }
    m = fmaxf(m, __shfl_xor(m, 16));
    m = fmaxf(m, __shfl_xor(m, 32));
    pmax[tc] = m;
  }
  if (lane < 16) {
#pragma unroll
    for (int tc = 0; tc < 16; ++tc) partials[w * 256 + tc * 16 + lane] = pmax[tc];
  }
  __syncthreads();
  if (tid < 256) {
    float m = partials[tid];
#pragma unroll
    for (int i = 1; i < 16; ++i) m = fmaxf(m, partials[i * 256 + tid]);
    gmax[tid] = m;
  }
  __syncthreads();

  float psum[16];
#pragma unroll
  for (int tc = 0; tc < 16; ++tc) {
    float s = 0.f;
    if (tc <= w) {
      float gm = gmax[tc * 16 + lm];
#pragma unroll
      for (int r = 0; r < 4; ++r) {
        float e = (acc[tc][r] > -1e29f) ? __expf(acc[tc][r] - gm) : 0.f;
        acc[tc][r] = e;
        s += e;
      }
    }
    s += __shfl_xor(s, 16);
    s += __shfl_xor(s, 32);
    psum[tc] = s;
  }
  if (lane < 16) {
#pragma unroll
    for (int tc = 0; tc < 16; ++tc) partials[w * 256 + tc * 16 + lane] = psum[tc];
  }
  __syncthreads();
  if (tid < 256) {
    float s = partials[tid];
#pragma unroll
    for (int i = 1; i < 16; ++i) s += partials[i * 256 + tid];
    linv[tid] = 1.f / s;
  }
  __syncthreads();

  {
    int s = tid >> 2, dg = (tid & 3) * 16;
    const u16* vrow = vp + (size_t)s * QKVLD + dg;
    u16 tmp[16];
    *(uint4*)&tmp[0] = *(const uint4*)(vrow);
    *(uint4*)&tmp[8] = *(const uint4*)(vrow + 8);
#pragma unroll
    for (int j = 0; j < 16; ++j) VT[(dg + j) * 264 + s] = tmp[j];
  }
  __syncthreads();

  u16* mst = stage + w * 640;
  floatx4 oacc[4];
#pragma unroll
  for (int nt = 0; nt < 4; ++nt) oacc[nt] = zero4;

#pragma unroll
  for (int c = 0; c < 8; ++c) {
    if (2 * c <= w) {
#pragma unroll
      for (int tt = 0; tt < 2; ++tt) {
        int tc = 2 * c + tt;
        float li = (tc <= w) ? linv[tc * 16 + lm] : 0.f;
#pragma unroll
        for (int r = 0; r < 4; ++r) {
          float pv = (tc <= w) ? acc[tc][r] * li : 0.f;
          mst[(qd * 4 + r) * 40 + tt * 16 + lm] = f2bf(pv);
        }
      }
      asm volatile("s_waitcnt lgkmcnt(0)" ::: "memory");
      short8 pf = *(const short8*)&mst[lm * 40 + qd * 8];
#pragma unroll
      for (int nt = 0; nt < 4; ++nt) {
        short8 vf = *(const short8*)&VT[(nt * 16 + lm) * 264 + c * 32 + qd * 8];
        oacc[nt] = __builtin_amdgcn_mfma_f32_16x16x32_bf16(pf, vf, oacc[nt], 0, 0, 0);
      }
      asm volatile("" ::: "memory");
    }
  }

  u16* ob = out + rowbase * CCH + h * HSZ;
#pragma unroll
  for (int nt = 0; nt < 4; ++nt) {
#pragma unroll
    for (int r = 0; r < 4; ++r) {
      int t = 16 * w + qd * 4 + r;
      ob[(size_t)t * CCH + nt * 16 + lm] = f2bf(oacc[nt][r]);
    }
  }
}

// ---------------- launch ----------------
extern "C" void kernel_launch(void* const* d_in, const int* in_sizes, int n_in,
                              void* d_out, int out_size, void* d_ws, size_t ws_size,
                              hipStream_t stream) {
  const float* x     = (const float*)d_in[0];
  const float* wq    = (const float*)d_in[1];
  const float* wk    = (const float*)d_in[2];
  const float* wv    = (const float*)d_in[3];
  const float* wproj = (const float*)d_in[4];
  const float* bproj = (const float*)d_in[5];
  const float* w1    = (const float*)d_in[6];
  const float* b1    = (const float*)d_in[7];
  const float* w2    = (const float*)d_in[8];
  const float* b2    = (const float*)d_in[9];
  const float* ln1g  = (const float*)d_in[10];
  const float* ln1b  = (const float*)d_in[11];
  const float* ln2g  = (const float*)d_in[12];
  const float* ln2b  = (const float*)d_in[13];
  float* out = (float*)d_out;
  (void)in_sizes; (void)n_in; (void)out_size; (void)ws_size;

  char* ws = (char*)d_ws;
  size_t off = 0;
  auto alloc = [&](size_t bytes) -> void* {
    void* p = ws + off;
    off += (bytes + 255) & ~(size_t)255;
    return p;
  };

  u16* wqkv_t = (u16*)alloc((size_t)QKVLD * CCH * 2);         // (1152,384)
  u16* wp_t   = (u16*)alloc((size_t)CCH * CCH * 2);           // (384,384)
  u16* w1_t   = (u16*)alloc((size_t)4 * CCH * CCH * 2);       // (1536,384)
  u16* w2_t   = (u16*)alloc((size_t)CCH * 4 * CCH * 2);       // (384,1536)
  u16*   h_b  = (u16*)alloc((size_t)BTT * CCH * 2);           // LN1 / attn-out / LN2
  u16*   x2   = (u16*)alloc((size_t)BTT * CCH * 2);           // bf16 residual stream
  u16*   qkv_b = (u16*)alloc((size_t)BTT * 4 * CCH * 2);      // (BT,1152) then u (BT,1536)
  u16*   u_b   = qkv_b;

  repack_all<<<5760, 256, 0, stream>>>(wq, wk, wv, wproj, w1, w2,
                                       wqkv_t, wp_t, w1_t, w2_t);

  // LN1 -> h
  ln_kernel<0><<<BTT / 4, 256, 0, stream>>>(x, ln1g, ln1b, h_b);

  // fused QKV: (BT,1152)
  gemm_mfma<0, 0, 0, 1, 0><<<dim3(9, 128), 256, 0, stream>>>(h_b, wqkv_t, nullptr, nullptr,
                                                             qkv_b, BTT, QKVLD, CCH);
  // attention -> h_b (h dead)
  attn_mfma<<<BB * NHH, 1024, 0, stream>>>(qkv_b, h_b);

  // x2 = x + attn @ wproj + bproj  (bf16 out)
  gemm_mfma<1, 1, 0, 1, 0><<<dim3(3, 128), 256, 0, stream>>>(h_b, wp_t, bproj, x, x2,
                                                             BTT, CCH, CCH);
  // LN2 -> h_b (attn dead)
  ln_kernel<1><<<BTT / 4, 256, 0, stream>>>(x2, ln2g, ln2b, h_b);

  // u = relu(h2 @ w1 + b1): (BT,1536)
  gemm_mfma<1, 0, 1, 1, 0><<<dim3(12, 128), 256, 0, stream>>>(h_b, w1_t, b1, nullptr, u_b,
                                                              BTT, 4 * CCH, CCH);
  // out = x2 + u @ w2 + b2  (fp32 out, bf16 res)
  gemm_mfma<1, 1, 0, 0, 1><<<dim3(3, 128), 256, 0, stream>>>(u_b, w2_t, b2, x2, out,
                                                             BTT, CCH, 4 * CCH);
}